// Round 1
// 7419.421 us; speedup vs baseline: 1.7387x; 1.7387x over previous
//
#include <hip/hip_runtime.h>
#include <stdint.h>

#define Bsz 128
#define Lsz 1024
#define Hsz 256
#define HB  (Bsz * Hsz)   // 32768 elems = one parity buffer

typedef __attribute__((ext_vector_type(8))) short bf16x8;
typedef __attribute__((ext_vector_type(4))) float f32x4;

__device__ __forceinline__ unsigned short f2bf(float f) {
    union { float f; uint32_t u; } v; v.f = f;
    uint32_t u = v.u;
    return (unsigned short)((u + 0x7FFFu + ((u >> 16) & 1u)) >> 16);  // RNE
}

__device__ __forceinline__ bf16x8 load_wfrag(const float* __restrict__ W, int row, int kb) {
    const float4* p = (const float4*)(W + row * Hsz + kb);
    float4 a = p[0], b = p[1];
    bf16x8 r;
    r[0] = (short)f2bf(a.x); r[1] = (short)f2bf(a.y);
    r[2] = (short)f2bf(a.z); r[3] = (short)f2bf(a.w);
    r[4] = (short)f2bf(b.x); r[5] = (short)f2bf(b.y);
    r[6] = (short)f2bf(b.z); r[7] = (short)f2bf(b.w);
    return r;
}

__device__ __forceinline__ float sigm(float x) { return 1.0f / (1.0f + __expf(-x)); }
__device__ __forceinline__ float tanhf_(float x) { return 1.0f - 2.0f / (1.0f + __expf(2.0f * x)); }

__device__ __forceinline__ void mm_step(bf16x8 a, const bf16x8 (&W)[3][8], int kt,
                                        f32x4& r, f32x4& z, f32x4& n) {
    r = __builtin_amdgcn_mfma_f32_16x16x32_bf16(a, W[0][kt], r, 0, 0, 0);
    z = __builtin_amdgcn_mfma_f32_16x16x32_bf16(a, W[1][kt], z, 0, 0, 0);
    n = __builtin_amdgcn_mfma_f32_16x16x32_bf16(a, W[2][kt], n, 0, 0, 0);
}

// --- device-scope (sc1) data path: h exchange bypasses the incoherent L1 /
// per-XCD-L2 dirtiness problem entirely, so NO buffer_inv / buffer_wbl2 is
// needed. Ordering is vmcnt(0) before the (relaxed) flag store. ---

// issue a 16B device-scope load; caller must s_waitcnt vmcnt(0) (+sched_barrier)
// before consuming the result.
__device__ __forceinline__ bf16x8 ld_h_sc1(const unsigned short* p) {
    bf16x8 r;
    asm volatile("global_load_dwordx4 %0, %1, off sc1" : "=v"(r) : "v"(p));
    return r;
}

__device__ __forceinline__ void st_h_sc1(unsigned short* p, unsigned short v) {
    unsigned int d = v;
    asm volatile("global_store_short %0, %1, off sc1" :: "v"(p), "v"(d) : "memory");
}

__device__ __forceinline__ void drain_stores_then_flag(int* fp, int val, int ln) {
    // all lanes wait for their own sc1 h-stores to reach the coherent point,
    // then one lane publishes the flag (relaxed agent store == sc1, no wbl2).
    asm volatile("s_waitcnt vmcnt(0)" ::: "memory");
    if (ln == 0)
        __hip_atomic_store(fp, val, __ATOMIC_RELAXED, __HIP_MEMORY_SCOPE_AGENT);
}

// all 64 lanes poll flag[ln&15]; relaxed only — data is read with sc1 loads so
// no acquire fence (buffer_inv) is required.
__device__ __forceinline__ void waitflags16(int* f, int target, int ln) {
    const int idx = ln & 15;
    while (__hip_atomic_load(f + idx, __ATOMIC_RELAXED, __HIP_MEMORY_SCOPE_AGENT) < target) { }
    asm volatile("" ::: "memory");
}

__global__ void init_ws(const float* __restrict__ h0in, int* flags,
                        unsigned short* h0buf, unsigned short* h1buf) {
    int i = blockIdx.x * blockDim.x + threadIdx.x;  // 0..32767
    if (i < 256) flags[i] = 0;                      // flags0[128] + flags1[128]
    h0buf[HB + i] = f2bf(h0in[i]);                  // parity-1 buffers hold h(-1)
    h1buf[HB + i] = f2bf(h0in[HB + i]);
}

// Persistent 2-layer GRU. Grid 64 = 8 batch-groups x 8 column-parts; part p of
// group g has blockIdx = p*8+g so all parts of a group land on XCD g (L2-local
// h exchange). 512 threads = 8 waves: wave = (mat = wv&3, jt = wv>>2).
// mat: 0=W_ih0 (gi0), 1=W_hh0 (gh0 + layer-0 gate owner), 2=W_ih1 (gi1),
//      3=W_hh1 (gh1 + layer-1 gate owner). Each wave's weight slice: 3 gates x
// 16 cols x 256 K bf16 = 24 frags = 96 VGPRs, register-resident (no spill: cap
// 256 at 2 waves/SIMD).
__global__ __launch_bounds__(512, 2) void gru2_persist(
    const float* __restrict__ x, const float* __restrict__ h0in,
    const float* __restrict__ wih0, const float* __restrict__ whh0,
    const float* __restrict__ bih0, const float* __restrict__ bhh0,
    const float* __restrict__ wih1, const float* __restrict__ whh1,
    const float* __restrict__ bih1, const float* __restrict__ bhh1,
    float* __restrict__ out,
    int* flags0, unsigned short* h0buf, unsigned short* h1buf)
{
    __shared__ float lds0[3][2][16][16];  // gi0 accums: [gate][jt][row][col]
    __shared__ float lds1[3][2][16][16];  // gi1 accums

    const int tid = threadIdx.x;
    const int wv = tid >> 6, ln = tid & 63;
    const int lr = ln & 15, quad = ln >> 4;
    const int g = blockIdx.x & 7, p = blockIdx.x >> 3;
    const int mat = wv & 3, jt = wv >> 2;
    const int b0 = g << 4;                         // batch rows [b0, b0+16)
    const int jabs = (p << 5) + (jt << 4) + lr;    // this lane's H column
    int* flags1 = flags0 + 128;
    int* f0g = flags0 + (g << 4);
    int* f1g = flags1 + (g << 4);

    // resident weight slice for this wave's matrix
    const float* Wm = (mat == 0) ? wih0 : (mat == 1) ? whh0 : (mat == 2) ? wih1 : whh1;
    bf16x8 Wf[3][8];
#pragma unroll
    for (int gg = 0; gg < 3; ++gg)
#pragma unroll
        for (int kt = 0; kt < 8; ++kt)
            Wf[gg][kt] = load_wfrag(Wm, gg * Hsz + jabs, (kt << 5) + (quad << 3));

    // gate-owner waves: fp32 h master (C/D layout: col=lane&15, row=quad*4+q) + biases
    float hp[4] = {0.f, 0.f, 0.f, 0.f};
    float bsr = 0.f, bsz_ = 0.f, bin_ = 0.f, bhn_ = 0.f;
    if (mat == 1) {
#pragma unroll
        for (int q = 0; q < 4; ++q) hp[q] = h0in[(b0 + (quad << 2) + q) * Hsz + jabs];
        bsr = bih0[jabs] + bhh0[jabs];
        bsz_ = bih0[Hsz + jabs] + bhh0[Hsz + jabs];
        bin_ = bih0[2 * Hsz + jabs];
        bhn_ = bhh0[2 * Hsz + jabs];
    } else if (mat == 3) {
#pragma unroll
        for (int q = 0; q < 4; ++q) hp[q] = h0in[HB + (b0 + (quad << 2) + q) * Hsz + jabs];
        bsr = bih1[jabs] + bhh1[jabs];
        bsz_ = bih1[Hsz + jabs] + bhh1[Hsz + jabs];
        bin_ = bih1[2 * Hsz + jabs];
        bhn_ = bhh1[2 * Hsz + jabs];
    }

    // x prefetch (mat==0 only): one step ahead, raw fp32 in regs (64 VGPRs)
    const float* xrow = x + (size_t)(b0 + lr) * Lsz * Hsz;  // + t*256 + k
    float4 xpre[16];
    if (mat == 0) {
#pragma unroll
        for (int kt = 0; kt < 8; ++kt) {
            const float* s = xrow + (kt << 5) + (quad << 3);
            xpre[2 * kt] = *(const float4*)(s);
            xpre[2 * kt + 1] = *(const float4*)(s + 4);
        }
    }

#pragma unroll 1
    for (int t = 0; t < Lsz; ++t) {
        const int par_w = t & 1;
        const unsigned short* h0r = h0buf + (par_w ^ 1) * HB;
        unsigned short* h0w = h0buf + par_w * HB;
        const unsigned short* h1r = h1buf + (par_w ^ 1) * HB;
        unsigned short* h1w = h1buf + par_w * HB;

        f32x4 ar = {0.f, 0.f, 0.f, 0.f}, az = {0.f, 0.f, 0.f, 0.f}, an = {0.f, 0.f, 0.f, 0.f};

        // ---- stage 1 ----
        if (mat == 0) {                       // gi0 = x_t @ Wih0^T (prefetched x)
#pragma unroll
            for (int kt = 0; kt < 8; ++kt) {
                float4 u = xpre[2 * kt], v = xpre[2 * kt + 1];
                bf16x8 a;
                a[0] = (short)f2bf(u.x); a[1] = (short)f2bf(u.y);
                a[2] = (short)f2bf(u.z); a[3] = (short)f2bf(u.w);
                a[4] = (short)f2bf(v.x); a[5] = (short)f2bf(v.y);
                a[6] = (short)f2bf(v.z); a[7] = (short)f2bf(v.w);
                mm_step(a, Wf, kt, ar, az, an);
            }
#pragma unroll
            for (int q = 0; q < 4; ++q) {
                lds0[0][jt][(quad << 2) + q][lr] = ar[q];
                lds0[1][jt][(quad << 2) + q][lr] = az[q];
                lds0[2][jt][(quad << 2) + q][lr] = an[q];
            }
        } else if (mat == 1) {                // gh0 = h0(t-1) @ Whh0^T
            waitflags16(f0g, t, ln);
            bf16x8 av[8];
#pragma unroll
            for (int kt = 0; kt < 8; ++kt)
                av[kt] = ld_h_sc1(h0r + (b0 + lr) * Hsz + (kt << 5) + (quad << 3));
            asm volatile("s_waitcnt vmcnt(0)" ::: "memory");
            __builtin_amdgcn_sched_barrier(0);
#pragma unroll
            for (int kt = 0; kt < 8; ++kt)
                mm_step(av[kt], Wf, kt, ar, az, an);
        } else if (mat == 3) {                // gh1 = h1(t-1) @ Whh1^T (overlaps layer 0)
            waitflags16(f1g, t, ln);
            bf16x8 av[8];
#pragma unroll
            for (int kt = 0; kt < 8; ++kt)
                av[kt] = ld_h_sc1(h1r + (b0 + lr) * Hsz + (kt << 5) + (quad << 3));
            asm volatile("s_waitcnt vmcnt(0)" ::: "memory");
            __builtin_amdgcn_sched_barrier(0);
#pragma unroll
            for (int kt = 0; kt < 8; ++kt)
                mm_step(av[kt], Wf, kt, ar, az, an);
        }
        __syncthreads();  // barrier 1: lds0 ready; lds1 free for reuse

        // ---- stage 2 ----
        if (mat == 1) {                       // layer-0 gates -> h0(t), broadcast
#pragma unroll
            for (int q = 0; q < 4; ++q) {
                float gir = lds0[0][jt][(quad << 2) + q][lr];
                float giz = lds0[1][jt][(quad << 2) + q][lr];
                float gin = lds0[2][jt][(quad << 2) + q][lr];
                float r = sigm(gir + ar[q] + bsr);
                float z = sigm(giz + az[q] + bsz_);
                float n = tanhf_(gin + bin_ + r * (an[q] + bhn_));
                float h = (1.0f - z) * n + z * hp[q];
                hp[q] = h;
                st_h_sc1(&h0w[(b0 + (quad << 2) + q) * Hsz + jabs], f2bf(h));
            }
            drain_stores_then_flag(f0g + (p << 1) + jt, t + 1, ln);
        } else if (mat == 2) {                // gi1 = h0(t) @ Wih1^T
            waitflags16(f0g, t + 1, ln);
            bf16x8 av[8];
#pragma unroll
            for (int kt = 0; kt < 8; ++kt)
                av[kt] = ld_h_sc1(h0w + (b0 + lr) * Hsz + (kt << 5) + (quad << 3));
            asm volatile("s_waitcnt vmcnt(0)" ::: "memory");
            __builtin_amdgcn_sched_barrier(0);
#pragma unroll
            for (int kt = 0; kt < 8; ++kt)
                mm_step(av[kt], Wf, kt, ar, az, an);
#pragma unroll
            for (int q = 0; q < 4; ++q) {
                lds1[0][jt][(quad << 2) + q][lr] = ar[q];
                lds1[1][jt][(quad << 2) + q][lr] = az[q];
                lds1[2][jt][(quad << 2) + q][lr] = an[q];
            }
        } else if (mat == 0) {                // prefetch x(t+1)
            const int tp = (t + 1 < Lsz) ? (t + 1) : t;
            const float* xb = xrow + (size_t)tp * Hsz;
#pragma unroll
            for (int kt = 0; kt < 8; ++kt) {
                const float* s = xb + (kt << 5) + (quad << 3);
                xpre[2 * kt] = *(const float4*)(s);
                xpre[2 * kt + 1] = *(const float4*)(s + 4);
            }
        }
        __syncthreads();  // barrier 2: lds1 ready

        // ---- stage 3 ----
        if (mat == 3) {                       // layer-1 gates -> h1(t), broadcast + output
            float hv[4];
#pragma unroll
            for (int q = 0; q < 4; ++q) {
                float gir = lds1[0][jt][(quad << 2) + q][lr];
                float giz = lds1[1][jt][(quad << 2) + q][lr];
                float gin = lds1[2][jt][(quad << 2) + q][lr];
                float r = sigm(gir + ar[q] + bsr);
                float z = sigm(giz + az[q] + bsz_);
                float n = tanhf_(gin + bin_ + r * (an[q] + bhn_));
                float h = (1.0f - z) * n + z * hp[q];
                hp[q] = h;
                hv[q] = h;
                st_h_sc1(&h1w[(b0 + (quad << 2) + q) * Hsz + jabs], f2bf(h));
            }
            // release BEFORE output stores (flag guards h1buf only)
            drain_stores_then_flag(f1g + (p << 1) + jt, t + 1, ln);
#pragma unroll
            for (int q = 0; q < 4; ++q)
                out[((size_t)(b0 + (quad << 2) + q) * Lsz + t) * Hsz + jabs] = hv[q];
        }
    }

    // final hidden states: out tail = hN[2][B][H]
    float* hN = out + (size_t)Bsz * Lsz * Hsz;
    if (mat == 1) {
#pragma unroll
        for (int q = 0; q < 4; ++q)
            hN[(b0 + (quad << 2) + q) * Hsz + jabs] = hp[q];
    } else if (mat == 3) {
#pragma unroll
        for (int q = 0; q < 4; ++q)
            hN[HB + (b0 + (quad << 2) + q) * Hsz + jabs] = hp[q];
    }
}

extern "C" void kernel_launch(void* const* d_in, const int* in_sizes, int n_in,
                              void* d_out, int out_size, void* d_ws, size_t ws_size,
                              hipStream_t stream) {
    const float* xx   = (const float*)d_in[0];
    const float* h0   = (const float*)d_in[1];
    const float* wih0 = (const float*)d_in[2];
    const float* whh0 = (const float*)d_in[3];
    const float* bih0 = (const float*)d_in[4];
    const float* bhh0 = (const float*)d_in[5];
    const float* wih1 = (const float*)d_in[6];
    const float* whh1 = (const float*)d_in[7];
    const float* bih1 = (const float*)d_in[8];
    const float* bhh1 = (const float*)d_in[9];
    float* out = (float*)d_out;

    int* flags = (int*)d_ws;                                    // 256 ints
    unsigned short* h0buf = (unsigned short*)((char*)d_ws + 4096);   // [2][128][256] bf16
    unsigned short* h1buf = h0buf + 2 * HB;                          // [2][128][256] bf16

    init_ws<<<dim3(128), dim3(256), 0, stream>>>(h0, flags, h0buf, h1buf);
    gru2_persist<<<dim3(64), dim3(512), 0, stream>>>(xx, h0, wih0, whh0, bih0, bhh0,
                                                     wih1, whh1, bih1, bhh1, out,
                                                     flags, h0buf, h1buf);
}

// Round 4
// 6720.142 us; speedup vs baseline: 1.9196x; 1.1041x over previous
//
#include <hip/hip_runtime.h>
#include <stdint.h>

#define Bsz 128
#define Lsz 1024
#define Hsz 256
#define HB  (Bsz * Hsz)   // 32768 elems = one parity buffer

typedef __attribute__((ext_vector_type(8))) short bf16x8;
typedef __attribute__((ext_vector_type(4))) float f32x4;

__device__ __forceinline__ unsigned short f2bf(float f) {
    union { float f; uint32_t u; } v; v.f = f;
    uint32_t u = v.u;
    return (unsigned short)((u + 0x7FFFu + ((u >> 16) & 1u)) >> 16);  // RNE
}

__device__ __forceinline__ bf16x8 load_wfrag(const float* __restrict__ W, int row, int kb) {
    const float4* p = (const float4*)(W + row * Hsz + kb);
    float4 a = p[0], b = p[1];
    bf16x8 r;
    r[0] = (short)f2bf(a.x); r[1] = (short)f2bf(a.y);
    r[2] = (short)f2bf(a.z); r[3] = (short)f2bf(a.w);
    r[4] = (short)f2bf(b.x); r[5] = (short)f2bf(b.y);
    r[6] = (short)f2bf(b.z); r[7] = (short)f2bf(b.w);
    return r;
}

__device__ __forceinline__ float sigm(float x) { return 1.0f / (1.0f + __expf(-x)); }
__device__ __forceinline__ float tanhf_(float x) { return 1.0f - 2.0f / (1.0f + __expf(2.0f * x)); }

__device__ __forceinline__ void mm_step(bf16x8 a, const bf16x8 (&W)[3][8], int kt,
                                        f32x4& r, f32x4& z, f32x4& n) {
    r = __builtin_amdgcn_mfma_f32_16x16x32_bf16(a, W[0][kt], r, 0, 0, 0);
    z = __builtin_amdgcn_mfma_f32_16x16x32_bf16(a, W[1][kt], z, 0, 0, 0);
    n = __builtin_amdgcn_mfma_f32_16x16x32_bf16(a, W[2][kt], n, 0, 0, 0);
}

// --- device-scope (sc1) data path: h exchange bypasses the incoherent L1 /
// per-XCD-L2 dirtiness problem entirely, so NO buffer_inv / buffer_wbl2 is
// needed. Ordering is vmcnt(0) before the (relaxed) flag store. ---

__device__ __forceinline__ bf16x8 ld_h_sc1(const unsigned short* p) {
    bf16x8 r;
    asm volatile("global_load_dwordx4 %0, %1, off sc1" : "=v"(r) : "v"(p));
    return r;
}

__device__ __forceinline__ void st_h_sc1(unsigned short* p, unsigned short v) {
    unsigned int d = v;
    asm volatile("global_store_short %0, %1, off sc1" :: "v"(p), "v"(d) : "memory");
}

// Flag layout (replicated per consumer to kill same-line poll contention):
//   fl0 set: [8 groups][8 consumer parts][32 ints (128B-strided line)]
//   fl1 set: same, offset +2048 ints.
// Producer wave (g,p,jt): after vmcnt(0), lanes 0..7 store val to entry
// (p*2+jt) of consumer-part ln's line. One store instruction, 8 transactions
// to 8 distinct lines.
__device__ __forceinline__ void drain_stores_then_flag8(int* flg_base, int entry, int val, int ln) {
    asm volatile("s_waitcnt vmcnt(0)" ::: "memory");
    if (ln < 8)
        __hip_atomic_store(flg_base + (ln << 5) + entry, val,
                           __ATOMIC_RELAXED, __HIP_MEMORY_SCOPE_AGENT);
}

// all 64 lanes poll this block's own 16-entry line; check-first then s_sleep
// backoff (~128 cyc) so already-satisfied waits pay nothing and steady-state
// poll pressure on the MALL line is cut ~4x.
__device__ __forceinline__ void waitflags16(const int* f, int target, int ln) {
    const int idx = ln & 15;
    while (__hip_atomic_load(f + idx, __ATOMIC_RELAXED, __HIP_MEMORY_SCOPE_AGENT) < target) {
        __builtin_amdgcn_s_sleep(2);
    }
    asm volatile("" ::: "memory");
}

__global__ void init_ws(const float* __restrict__ h0in, int* flags,
                        unsigned short* h0buf, unsigned short* h1buf) {
    int i = blockIdx.x * blockDim.x + threadIdx.x;  // 0..32767
    if (i < 4096) flags[i] = 0;                     // fl0[2048] + fl1[2048] ints
    h0buf[HB + i] = f2bf(h0in[i]);                  // parity-1 buffers hold h(-1)
    h1buf[HB + i] = f2bf(h0in[HB + i]);
}

// Persistent 2-layer GRU. Grid 64 = 8 batch-groups x 8 column-parts; part p of
// group g has blockIdx = p*8+g so all parts of a group land on XCD g (L2-local
// h exchange). 512 threads = 8 waves: wave = (mat = wv&3, jt = wv>>2).
// mat: 0=W_ih0 (gi0), 1=W_hh0 (gh0 + layer-0 gate owner), 2=W_ih1 (gi1),
//      3=W_hh1 (gh1 + layer-1 gate owner). Each wave's weight slice: 3 gates x
// 16 cols x 256 K bf16 = 24 frags = 96 VGPRs, register-resident.
__global__ __launch_bounds__(512, 2) void gru2_persist(
    const float* __restrict__ x, const float* __restrict__ h0in,
    const float* __restrict__ wih0, const float* __restrict__ whh0,
    const float* __restrict__ bih0, const float* __restrict__ bhh0,
    const float* __restrict__ wih1, const float* __restrict__ whh1,
    const float* __restrict__ bih1, const float* __restrict__ bhh1,
    float* __restrict__ out,
    int* flags0, unsigned short* h0buf, unsigned short* h1buf)
{
    __shared__ float lds0[3][2][16][16];  // gi0 accums: [gate][jt][row][col]
    __shared__ float lds1[3][2][16][16];  // gi1 accums

    const int tid = threadIdx.x;
    const int wv = tid >> 6, ln = tid & 63;
    const int lr = ln & 15, quad = ln >> 4;
    const int g = blockIdx.x & 7, p = blockIdx.x >> 3;
    const int mat = wv & 3, jt = wv >> 2;
    const int b0 = g << 4;                         // batch rows [b0, b0+16)
    const int jabs = (p << 5) + (jt << 4) + lr;    // this lane's H column

    int* fl0g = flags0 + (g << 8);                 // this group's 8 fl0 lines
    int* fl1g = flags0 + 2048 + (g << 8);          // this group's 8 fl1 lines
    int* myf0 = fl0g + (p << 5);                   // this block's own fl0 line
    int* myf1 = fl1g + (p << 5);                   // this block's own fl1 line

    // resident weight slice for this wave's matrix
    const float* Wm = (mat == 0) ? wih0 : (mat == 1) ? whh0 : (mat == 2) ? wih1 : whh1;
    bf16x8 Wf[3][8];
#pragma unroll
    for (int gg = 0; gg < 3; ++gg)
#pragma unroll
        for (int kt = 0; kt < 8; ++kt)
            Wf[gg][kt] = load_wfrag(Wm, gg * Hsz + jabs, (kt << 5) + (quad << 3));

    // gate-owner waves: fp32 h master (C/D layout: col=lane&15, row=quad*4+q) + biases
    float hp[4] = {0.f, 0.f, 0.f, 0.f};
    float bsr = 0.f, bsz_ = 0.f, bin_ = 0.f, bhn_ = 0.f;
    if (mat == 1) {
#pragma unroll
        for (int q = 0; q < 4; ++q) hp[q] = h0in[(b0 + (quad << 2) + q) * Hsz + jabs];
        bsr = bih0[jabs] + bhh0[jabs];
        bsz_ = bih0[Hsz + jabs] + bhh0[Hsz + jabs];
        bin_ = bih0[2 * Hsz + jabs];
        bhn_ = bhh0[2 * Hsz + jabs];
    } else if (mat == 3) {
#pragma unroll
        for (int q = 0; q < 4; ++q) hp[q] = h0in[HB + (b0 + (quad << 2) + q) * Hsz + jabs];
        bsr = bih1[jabs] + bhh1[jabs];
        bsz_ = bih1[Hsz + jabs] + bhh1[Hsz + jabs];
        bin_ = bih1[2 * Hsz + jabs];
        bhn_ = bhh1[2 * Hsz + jabs];
    }

    // x prefetch (mat==0 only): one step ahead, raw fp32 in regs (64 VGPRs)
    const float* xrow = x + (size_t)(b0 + lr) * Lsz * Hsz;  // + t*256 + k
    float4 xpre[16];
    if (mat == 0) {
#pragma unroll
        for (int kt = 0; kt < 8; ++kt) {
            const float* s = xrow + (kt << 5) + (quad << 3);
            xpre[2 * kt] = *(const float4*)(s);
            xpre[2 * kt + 1] = *(const float4*)(s + 4);
        }
    }

#pragma unroll 1
    for (int t = 0; t < Lsz; ++t) {
        const int par_w = t & 1;
        const unsigned short* h0r = h0buf + (par_w ^ 1) * HB;
        unsigned short* h0w = h0buf + par_w * HB;
        const unsigned short* h1r = h1buf + (par_w ^ 1) * HB;
        unsigned short* h1w = h1buf + par_w * HB;

        f32x4 ar = {0.f, 0.f, 0.f, 0.f}, az = {0.f, 0.f, 0.f, 0.f}, an = {0.f, 0.f, 0.f, 0.f};

        // ---- stage 1 ----
        if (mat == 0) {                       // gi0 = x_t @ Wih0^T (prefetched x)
#pragma unroll
            for (int kt = 0; kt < 8; ++kt) {
                float4 u = xpre[2 * kt], v = xpre[2 * kt + 1];
                bf16x8 a;
                a[0] = (short)f2bf(u.x); a[1] = (short)f2bf(u.y);
                a[2] = (short)f2bf(u.z); a[3] = (short)f2bf(u.w);
                a[4] = (short)f2bf(v.x); a[5] = (short)f2bf(v.y);
                a[6] = (short)f2bf(v.z); a[7] = (short)f2bf(v.w);
                mm_step(a, Wf, kt, ar, az, an);
            }
#pragma unroll
            for (int q = 0; q < 4; ++q) {
                lds0[0][jt][(quad << 2) + q][lr] = ar[q];
                lds0[1][jt][(quad << 2) + q][lr] = az[q];
                lds0[2][jt][(quad << 2) + q][lr] = an[q];
            }
        } else if (mat == 1) {                // gh0 = h0(t-1) @ Whh0^T
            waitflags16(myf0, t, ln);
            bf16x8 av[8];
#pragma unroll
            for (int kt = 0; kt < 8; ++kt)
                av[kt] = ld_h_sc1(h0r + (b0 + lr) * Hsz + (kt << 5) + (quad << 3));
            asm volatile("s_waitcnt vmcnt(0)" ::: "memory");
            __builtin_amdgcn_sched_barrier(0);
#pragma unroll
            for (int kt = 0; kt < 8; ++kt)
                mm_step(av[kt], Wf, kt, ar, az, an);
        } else if (mat == 3) {                // gh1 = h1(t-1) @ Whh1^T (overlaps layer 0)
            waitflags16(myf1, t, ln);
            bf16x8 av[8];
#pragma unroll
            for (int kt = 0; kt < 8; ++kt)
                av[kt] = ld_h_sc1(h1r + (b0 + lr) * Hsz + (kt << 5) + (quad << 3));
            asm volatile("s_waitcnt vmcnt(0)" ::: "memory");
            __builtin_amdgcn_sched_barrier(0);
#pragma unroll
            for (int kt = 0; kt < 8; ++kt)
                mm_step(av[kt], Wf, kt, ar, az, an);
        }
        __syncthreads();  // barrier 1: lds0 ready; lds1 free for reuse

        // ---- stage 2 ----
        if (mat == 1) {                       // layer-0 gates -> h0(t), broadcast
#pragma unroll
            for (int q = 0; q < 4; ++q) {
                float gir = lds0[0][jt][(quad << 2) + q][lr];
                float giz = lds0[1][jt][(quad << 2) + q][lr];
                float gin = lds0[2][jt][(quad << 2) + q][lr];
                float r = sigm(gir + ar[q] + bsr);
                float z = sigm(giz + az[q] + bsz_);
                float n = tanhf_(gin + bin_ + r * (an[q] + bhn_));
                float h = (1.0f - z) * n + z * hp[q];
                hp[q] = h;
                st_h_sc1(&h0w[(b0 + (quad << 2) + q) * Hsz + jabs], f2bf(h));
            }
            drain_stores_then_flag8(fl0g, (p << 1) + jt, t + 1, ln);
        } else if (mat == 2) {                // gi1 = h0(t) @ Wih1^T
            waitflags16(myf0, t + 1, ln);
            bf16x8 av[8];
#pragma unroll
            for (int kt = 0; kt < 8; ++kt)
                av[kt] = ld_h_sc1(h0w + (b0 + lr) * Hsz + (kt << 5) + (quad << 3));
            asm volatile("s_waitcnt vmcnt(0)" ::: "memory");
            __builtin_amdgcn_sched_barrier(0);
#pragma unroll
            for (int kt = 0; kt < 8; ++kt)
                mm_step(av[kt], Wf, kt, ar, az, an);
#pragma unroll
            for (int q = 0; q < 4; ++q) {
                lds1[0][jt][(quad << 2) + q][lr] = ar[q];
                lds1[1][jt][(quad << 2) + q][lr] = az[q];
                lds1[2][jt][(quad << 2) + q][lr] = an[q];
            }
        } else if (mat == 0) {                // prefetch x(t+1)
            const int tp = (t + 1 < Lsz) ? (t + 1) : t;
            const float* xb = xrow + (size_t)tp * Hsz;
#pragma unroll
            for (int kt = 0; kt < 8; ++kt) {
                const float* s = xb + (kt << 5) + (quad << 3);
                xpre[2 * kt] = *(const float4*)(s);
                xpre[2 * kt + 1] = *(const float4*)(s + 4);
            }
        }
        __syncthreads();  // barrier 2: lds1 ready

        // ---- stage 3 ----
        if (mat == 3) {                       // layer-1 gates -> h1(t), broadcast + output
            float hv[4];
#pragma unroll
            for (int q = 0; q < 4; ++q) {
                float gir = lds1[0][jt][(quad << 2) + q][lr];
                float giz = lds1[1][jt][(quad << 2) + q][lr];
                float gin = lds1[2][jt][(quad << 2) + q][lr];
                float r = sigm(gir + ar[q] + bsr);
                float z = sigm(giz + az[q] + bsz_);
                float n = tanhf_(gin + bin_ + r * (an[q] + bhn_));
                float h = (1.0f - z) * n + z * hp[q];
                hp[q] = h;
                hv[q] = h;
                st_h_sc1(&h1w[(b0 + (quad << 2) + q) * Hsz + jabs], f2bf(h));
            }
            // release BEFORE output stores (flag guards h1buf only)
            drain_stores_then_flag8(fl1g, (p << 1) + jt, t + 1, ln);
#pragma unroll
            for (int q = 0; q < 4; ++q)
                out[((size_t)(b0 + (quad << 2) + q) * Lsz + t) * Hsz + jabs] = hv[q];
        }
    }

    // final hidden states: out tail = hN[2][B][H]
    float* hN = out + (size_t)Bsz * Lsz * Hsz;
    if (mat == 1) {
#pragma unroll
        for (int q = 0; q < 4; ++q)
            hN[(b0 + (quad << 2) + q) * Hsz + jabs] = hp[q];
    } else if (mat == 3) {
#pragma unroll
        for (int q = 0; q < 4; ++q)
            hN[HB + (b0 + (quad << 2) + q) * Hsz + jabs] = hp[q];
    }
}

extern "C" void kernel_launch(void* const* d_in, const int* in_sizes, int n_in,
                              void* d_out, int out_size, void* d_ws, size_t ws_size,
                              hipStream_t stream) {
    const float* xx   = (const float*)d_in[0];
    const float* h0   = (const float*)d_in[1];
    const float* wih0 = (const float*)d_in[2];
    const float* whh0 = (const float*)d_in[3];
    const float* bih0 = (const float*)d_in[4];
    const float* bhh0 = (const float*)d_in[5];
    const float* wih1 = (const float*)d_in[6];
    const float* whh1 = (const float*)d_in[7];
    const float* bih1 = (const float*)d_in[8];
    const float* bhh1 = (const float*)d_in[9];
    float* out = (float*)d_out;

    int* flags = (int*)d_ws;                                          // 16 KB flag region
    unsigned short* h0buf = (unsigned short*)((char*)d_ws + 16384);   // [2][128][256] bf16
    unsigned short* h1buf = h0buf + 2 * HB;                           // [2][128][256] bf16

    init_ws<<<dim3(128), dim3(256), 0, stream>>>(h0, flags, h0buf, h1buf);
    gru2_persist<<<dim3(64), dim3(512), 0, stream>>>(xx, h0, wih0, whh0, bih0, bhh0,
                                                     wih1, whh1, bih1, bhh1, out,
                                                     flags, h0buf, h1buf);
}

// Round 6
// 4554.312 us; speedup vs baseline: 2.8325x; 1.4756x over previous
//
#include <hip/hip_runtime.h>
#include <stdint.h>

#define Bsz 128
#define Lsz 1024
#define Hsz 256
#define HB  (Bsz * Hsz)   // 32768 elems = one parity buffer

typedef __attribute__((ext_vector_type(8))) short bf16x8;
typedef __attribute__((ext_vector_type(4))) float f32x4;

__device__ __forceinline__ unsigned short f2bf(float f) {
    union { float f; uint32_t u; } v; v.f = f;
    uint32_t u = v.u;
    return (unsigned short)((u + 0x7FFFu + ((u >> 16) & 1u)) >> 16);  // RNE
}

__device__ __forceinline__ bf16x8 load_wfrag(const float* __restrict__ W, int row, int kb) {
    const float4* p = (const float4*)(W + row * Hsz + kb);
    float4 a = p[0], b = p[1];
    bf16x8 r;
    r[0] = (short)f2bf(a.x); r[1] = (short)f2bf(a.y);
    r[2] = (short)f2bf(a.z); r[3] = (short)f2bf(a.w);
    r[4] = (short)f2bf(b.x); r[5] = (short)f2bf(b.y);
    r[6] = (short)f2bf(b.z); r[7] = (short)f2bf(b.w);
    return r;
}

__device__ __forceinline__ float sigm(float x) { return 1.0f / (1.0f + __expf(-x)); }
__device__ __forceinline__ float tanhf_(float x) { return 1.0f - 2.0f / (1.0f + __expf(2.0f * x)); }

__device__ __forceinline__ void mm_step(bf16x8 a, const bf16x8 (&W)[3][8], int kt,
                                        f32x4& r, f32x4& z, f32x4& n) {
    r = __builtin_amdgcn_mfma_f32_16x16x32_bf16(a, W[0][kt], r, 0, 0, 0);
    z = __builtin_amdgcn_mfma_f32_16x16x32_bf16(a, W[1][kt], z, 0, 0, 0);
    n = __builtin_amdgcn_mfma_f32_16x16x32_bf16(a, W[2][kt], n, 0, 0, 0);
}

// --- device-scope (sc1) data path: h exchange bypasses the incoherent L1 /
// per-XCD-L2 dirtiness problem entirely, so NO buffer_inv / buffer_wbl2 is
// needed. Ordering is vmcnt(0) before the (relaxed) flag store. ---

__device__ __forceinline__ bf16x8 ld_h_sc1(const unsigned short* p) {
    bf16x8 r;
    asm volatile("global_load_dwordx4 %0, %1, off sc1" : "=v"(r) : "v"(p));
    return r;
}

__device__ __forceinline__ void st_h_sc1(unsigned short* p, unsigned short v) {
    unsigned int d = v;
    asm volatile("global_store_short %0, %1, off sc1" :: "v"(p), "v"(d) : "memory");
}

// Flag layout (replicated per consumer to kill same-line poll contention):
//   fl0 set: [8 groups][8 consumer parts][32 ints (128B-strided line)]
//   fl1 set: same, offset +2048 ints.
__device__ __forceinline__ void drain_stores_then_flag8(int* flg_base, int entry, int val, int ln) {
    asm volatile("s_waitcnt vmcnt(0)" ::: "memory");
    if (ln < 8)
        __hip_atomic_store(flg_base + (ln << 5) + entry, val,
                           __ATOMIC_RELAXED, __HIP_MEMORY_SCOPE_AGENT);
}

__device__ __forceinline__ void waitflags16(const int* f, int target, int ln) {
    const int idx = ln & 15;
    while (__hip_atomic_load(f + idx, __ATOMIC_RELAXED, __HIP_MEMORY_SCOPE_AGENT) < target) {
        __builtin_amdgcn_s_sleep(1);
    }
    asm volatile("" ::: "memory");
}

// REPLAY-BOUNDARY HARDENING: the main kernel reads flags and h(-1) through
// sc1 loads (MALL-direct). If init_ws wrote them with PLAIN stores, their
// visibility to those loads depends on the runtime's inter-dispatch L2
// writeback — under graph replay a consumer could observe the PREVIOUS
// replay's flag value (>= any target -> instant pass -> stale data read).
// Writing flags with agent-scope atomics and h(-1) with sc1 stores puts them
// AT the coherent point before init_ws retires, independent of runtime cache
// maintenance.
__global__ void init_ws(const float* __restrict__ h0in, int* flags,
                        unsigned short* h0buf, unsigned short* h1buf) {
    int i = blockIdx.x * blockDim.x + threadIdx.x;  // 0..32767
    if (i < 4096)
        __hip_atomic_store(flags + i, 0, __ATOMIC_RELAXED, __HIP_MEMORY_SCOPE_AGENT);
    st_h_sc1(&h0buf[HB + i], f2bf(h0in[i]));        // parity-1 buffers hold h(-1)
    st_h_sc1(&h1buf[HB + i], f2bf(h0in[HB + i]));
    asm volatile("s_waitcnt vmcnt(0)" ::: "memory");
}

// Persistent 2-layer GRU, layer-1 pipelined ONE STEP BEHIND layer 0.
// Iteration i: layer 0 computes h0(i) (i<Lsz); layer 1 computes h1(i-1) (i>=1).
// gh0(i), gi1(i-1) both consume h0(i-1) -> all four matmul waves run in
// stage 1 concurrently; stage 2 is only the two gate-owners' store+drain+flag
// (in parallel). Serial MALL round-trips per step: ~2-3 (was ~5-6).
// Grid 64 = 8 batch-groups x 8 column-parts. 512 threads = 8 waves:
// mat 0=W_ih0(gi0) 1=W_hh0(gh0+layer0 gates) 2=W_ih1(gi1) 3=W_hh1(gh1+layer1 gates).
__global__ __launch_bounds__(512, 2) void gru2_persist(
    const float* __restrict__ x, const float* __restrict__ h0in,
    const float* __restrict__ wih0, const float* __restrict__ whh0,
    const float* __restrict__ bih0, const float* __restrict__ bhh0,
    const float* __restrict__ wih1, const float* __restrict__ whh1,
    const float* __restrict__ bih1, const float* __restrict__ bhh1,
    float* __restrict__ out,
    int* flags0, unsigned short* h0buf, unsigned short* h1buf)
{
    __shared__ float lds0[3][2][16][16];  // gi0 accums: [gate][jt][row][col]
    __shared__ float lds1[3][2][16][16];  // gi1 accums

    const int tid = threadIdx.x;
    const int wv = tid >> 6, ln = tid & 63;
    const int lr = ln & 15, quad = ln >> 4;
    const int g = blockIdx.x & 7, p = blockIdx.x >> 3;
    const int mat = wv & 3, jt = wv >> 2;
    const int b0 = g << 4;                         // batch rows [b0, b0+16)
    const int jabs = (p << 5) + (jt << 4) + lr;    // this lane's H column

    int* fl0g = flags0 + (g << 8);                 // this group's 8 fl0 lines
    int* fl1g = flags0 + 2048 + (g << 8);          // this group's 8 fl1 lines
    int* myf0 = fl0g + (p << 5);                   // this block's own fl0 line
    int* myf1 = fl1g + (p << 5);                   // this block's own fl1 line

    // resident weight slice for this wave's matrix
    const float* Wm = (mat == 0) ? wih0 : (mat == 1) ? whh0 : (mat == 2) ? wih1 : whh1;
    bf16x8 Wf[3][8];
#pragma unroll
    for (int gg = 0; gg < 3; ++gg)
#pragma unroll
        for (int kt = 0; kt < 8; ++kt)
            Wf[gg][kt] = load_wfrag(Wm, gg * Hsz + jabs, (kt << 5) + (quad << 3));

    // gate-owner waves: fp32 h master (C/D layout: col=lane&15, row=quad*4+q) + biases
    float hp[4] = {0.f, 0.f, 0.f, 0.f};
    float bsr = 0.f, bsz_ = 0.f, bin_ = 0.f, bhn_ = 0.f;
    if (mat == 1) {
#pragma unroll
        for (int q = 0; q < 4; ++q) hp[q] = h0in[(b0 + (quad << 2) + q) * Hsz + jabs];
        bsr = bih0[jabs] + bhh0[jabs];
        bsz_ = bih0[Hsz + jabs] + bhh0[Hsz + jabs];
        bin_ = bih0[2 * Hsz + jabs];
        bhn_ = bhh0[2 * Hsz + jabs];
    } else if (mat == 3) {
#pragma unroll
        for (int q = 0; q < 4; ++q) hp[q] = h0in[HB + (b0 + (quad << 2) + q) * Hsz + jabs];
        bsr = bih1[jabs] + bhh1[jabs];
        bsz_ = bih1[Hsz + jabs] + bhh1[Hsz + jabs];
        bin_ = bih1[2 * Hsz + jabs];
        bhn_ = bhh1[2 * Hsz + jabs];
    }

    // x prefetch (mat==0 only): one step ahead, raw fp32 in regs (64 VGPRs)
    const float* xrow = x + (size_t)(b0 + lr) * Lsz * Hsz;  // + t*256 + k
    float4 xpre[16];
    if (mat == 0) {
#pragma unroll
        for (int kt = 0; kt < 8; ++kt) {
            const float* s = xrow + (kt << 5) + (quad << 3);
            xpre[2 * kt] = *(const float4*)(s);
            xpre[2 * kt + 1] = *(const float4*)(s + 4);
        }
    }

#pragma unroll 1
    for (int i = 0; i <= Lsz; ++i) {
        // h0(i) written to parity i&1; h0(i-1) read from parity (i-1)&1.
        const unsigned short* h0r = h0buf + ((i ^ 1) & 1) * HB;
        unsigned short* h0w = h0buf + (i & 1) * HB;
        // h1(i-1) written to parity (i-1)&1; h1(i-2) read from parity i&1.
        const unsigned short* h1r = h1buf + (i & 1) * HB;
        unsigned short* h1w = h1buf + ((i ^ 1) & 1) * HB;

        f32x4 ar = {0.f, 0.f, 0.f, 0.f}, az = {0.f, 0.f, 0.f, 0.f}, an = {0.f, 0.f, 0.f, 0.f};

        // ---- stage 1: all four matmuls concurrent ----
        if (mat == 0) {                       // gi0(i) = x_i @ Wih0^T (prefetched x)
            if (i < Lsz) {
#pragma unroll
                for (int kt = 0; kt < 8; ++kt) {
                    float4 u = xpre[2 * kt], v = xpre[2 * kt + 1];
                    bf16x8 a;
                    a[0] = (short)f2bf(u.x); a[1] = (short)f2bf(u.y);
                    a[2] = (short)f2bf(u.z); a[3] = (short)f2bf(u.w);
                    a[4] = (short)f2bf(v.x); a[5] = (short)f2bf(v.y);
                    a[6] = (short)f2bf(v.z); a[7] = (short)f2bf(v.w);
                    mm_step(a, Wf, kt, ar, az, an);
                }
#pragma unroll
                for (int q = 0; q < 4; ++q) {
                    lds0[0][jt][(quad << 2) + q][lr] = ar[q];
                    lds0[1][jt][(quad << 2) + q][lr] = az[q];
                    lds0[2][jt][(quad << 2) + q][lr] = an[q];
                }
            }
        } else if (mat == 1) {                // gh0(i) = h0(i-1) @ Whh0^T
            if (i < Lsz) {
                waitflags16(myf0, i, ln);
                bf16x8 av[8];
#pragma unroll
                for (int kt = 0; kt < 8; ++kt)
                    av[kt] = ld_h_sc1(h0r + (b0 + lr) * Hsz + (kt << 5) + (quad << 3));
                asm volatile("s_waitcnt vmcnt(0)" ::: "memory");
                __builtin_amdgcn_sched_barrier(0);
#pragma unroll
                for (int kt = 0; kt < 8; ++kt)
                    mm_step(av[kt], Wf, kt, ar, az, an);
            }
        } else if (mat == 2) {                // gi1(i-1) = h0(i-1) @ Wih1^T
            if (i) {
                waitflags16(myf0, i, ln);
                bf16x8 av[8];
#pragma unroll
                for (int kt = 0; kt < 8; ++kt)
                    av[kt] = ld_h_sc1(h0r + (b0 + lr) * Hsz + (kt << 5) + (quad << 3));
                asm volatile("s_waitcnt vmcnt(0)" ::: "memory");
                __builtin_amdgcn_sched_barrier(0);
#pragma unroll
                for (int kt = 0; kt < 8; ++kt)
                    mm_step(av[kt], Wf, kt, ar, az, an);
#pragma unroll
                for (int q = 0; q < 4; ++q) {
                    lds1[0][jt][(quad << 2) + q][lr] = ar[q];
                    lds1[1][jt][(quad << 2) + q][lr] = az[q];
                    lds1[2][jt][(quad << 2) + q][lr] = an[q];
                }
            }
        } else {                              // mat3: gh1(i-1) = h1(i-2) @ Whh1^T
            if (i) {
                waitflags16(myf1, i - 1, ln);
                bf16x8 av[8];
#pragma unroll
                for (int kt = 0; kt < 8; ++kt)
                    av[kt] = ld_h_sc1(h1r + (b0 + lr) * Hsz + (kt << 5) + (quad << 3));
                asm volatile("s_waitcnt vmcnt(0)" ::: "memory");
                __builtin_amdgcn_sched_barrier(0);
#pragma unroll
                for (int kt = 0; kt < 8; ++kt)
                    mm_step(av[kt], Wf, kt, ar, az, an);
            }
        }
        __syncthreads();  // barrier 1: lds0/lds1 ready for stage 2

        // ---- stage 2: both gate-owners in parallel ----
        if (mat == 1) {                       // layer-0 gates -> h0(i), broadcast
            if (i < Lsz) {
#pragma unroll
                for (int q = 0; q < 4; ++q) {
                    float gir = lds0[0][jt][(quad << 2) + q][lr];
                    float giz = lds0[1][jt][(quad << 2) + q][lr];
                    float gin = lds0[2][jt][(quad << 2) + q][lr];
                    float r = sigm(gir + ar[q] + bsr);
                    float z = sigm(giz + az[q] + bsz_);
                    float n = tanhf_(gin + bin_ + r * (an[q] + bhn_));
                    float h = (1.0f - z) * n + z * hp[q];
                    hp[q] = h;
                    st_h_sc1(&h0w[(b0 + (quad << 2) + q) * Hsz + jabs], f2bf(h));
                }
                drain_stores_then_flag8(fl0g, (p << 1) + jt, i + 1, ln);
            }
        } else if (mat == 3) {                // layer-1 gates -> h1(i-1), broadcast + output
            if (i) {
                float hv[4];
#pragma unroll
                for (int q = 0; q < 4; ++q) {
                    float gir = lds1[0][jt][(quad << 2) + q][lr];
                    float giz = lds1[1][jt][(quad << 2) + q][lr];
                    float gin = lds1[2][jt][(quad << 2) + q][lr];
                    float r = sigm(gir + ar[q] + bsr);
                    float z = sigm(giz + az[q] + bsz_);
                    float n = tanhf_(gin + bin_ + r * (an[q] + bhn_));
                    float h = (1.0f - z) * n + z * hp[q];
                    hp[q] = h;
                    hv[q] = h;
                    st_h_sc1(&h1w[(b0 + (quad << 2) + q) * Hsz + jabs], f2bf(h));
                }
                // release BEFORE output stores (flag guards h1buf only)
                drain_stores_then_flag8(fl1g, (p << 1) + jt, i, ln);
                const int t = i - 1;
#pragma unroll
                for (int q = 0; q < 4; ++q)
                    out[((size_t)(b0 + (quad << 2) + q) * Lsz + t) * Hsz + jabs] = hv[q];
            }
        } else if (mat == 0) {                // prefetch x(i+1)
            if (i + 1 < Lsz) {
                const float* xb = xrow + (size_t)(i + 1) * Hsz;
#pragma unroll
                for (int kt = 0; kt < 8; ++kt) {
                    const float* s = xb + (kt << 5) + (quad << 3);
                    xpre[2 * kt] = *(const float4*)(s);
                    xpre[2 * kt + 1] = *(const float4*)(s + 4);
                }
            }
        }
        __syncthreads();  // barrier 2: stage-2 LDS reads done; buffers reusable
    }

    // final hidden states: out tail = hN[2][B][H]
    float* hN = out + (size_t)Bsz * Lsz * Hsz;
    if (mat == 1) {
#pragma unroll
        for (int q = 0; q < 4; ++q)
            hN[(b0 + (quad << 2) + q) * Hsz + jabs] = hp[q];
    } else if (mat == 3) {
#pragma unroll
        for (int q = 0; q < 4; ++q)
            hN[HB + (b0 + (quad << 2) + q) * Hsz + jabs] = hp[q];
    }
}

extern "C" void kernel_launch(void* const* d_in, const int* in_sizes, int n_in,
                              void* d_out, int out_size, void* d_ws, size_t ws_size,
                              hipStream_t stream) {
    const float* xx   = (const float*)d_in[0];
    const float* h0   = (const float*)d_in[1];
    const float* wih0 = (const float*)d_in[2];
    const float* whh0 = (const float*)d_in[3];
    const float* bih0 = (const float*)d_in[4];
    const float* bhh0 = (const float*)d_in[5];
    const float* wih1 = (const float*)d_in[6];
    const float* whh1 = (const float*)d_in[7];
    const float* bih1 = (const float*)d_in[8];
    const float* bhh1 = (const float*)d_in[9];
    float* out = (float*)d_out;

    int* flags = (int*)d_ws;                                          // 16 KB flag region
    unsigned short* h0buf = (unsigned short*)((char*)d_ws + 16384);   // [2][128][256] bf16
    unsigned short* h1buf = h0buf + 2 * HB;                           // [2][128][256] bf16

    init_ws<<<dim3(128), dim3(256), 0, stream>>>(h0, flags, h0buf, h1buf);
    gru2_persist<<<dim3(64), dim3(512), 0, stream>>>(xx, h0, wih0, whh0, bih0, bhh0,
                                                     wih1, whh1, bih1, bhh1, out,
                                                     flags, h0buf, h1buf);
}